// Round 14
// baseline (141.969 us; speedup 1.0000x reference)
//
#include <hip/hip_runtime.h>
#include <hip/hip_bf16.h>
#include <hip/hip_fp8.h>

#define N_ROWS 8192
#define NZ 16384           // rows of Z = [An; Bn]
#define DIM 256
#define TAU_INV 2.0f
#define BT 128             // col tile width
#define AT 64              // row tile height (A strip)
#define NTILE 128          // NZ / BT  (col tiles)
#define SEGT 4             // col tiles per segment
#define NSEG 4224          // sum over ri of ceil((128 - (ri>>1))/4)
#define PSTRIDE 1152       // floats/segment: 2*64 row-partials + 4*2*128 col-partials

typedef float f32x4 __attribute__((ext_vector_type(4)));
typedef long lx2 __attribute__((ext_vector_type(2)));   // 16B = 2 fp8 MFMA operands

// ---------------------------------------------------------------------------
// Kernel 1: one WAVE per row. L2-normalize, scale by 16, quantize to OCP fp8
// e4m3, write Z8 K-INTERLEAVED: each 64B chunk stores its eight 8B K-groups
// as [g0 g4 g1 g5 g2 g6 g3 g7] so one 16B granule = operand pair (g, g+4)
// for two consecutive MFMA K-steps. pos[i] = (1/256)*dot(quantized an, bn).
// Also zeroes out[0] (stream-ordered before the fused reduce+loss).
// ---------------------------------------------------------------------------
__global__ __launch_bounds__(256) void normalize_kernel(
    const float* __restrict__ z1, const float* __restrict__ z2,
    unsigned char* __restrict__ Z8, float* __restrict__ pos,
    float* __restrict__ out)
{
    const int tid = threadIdx.x;
    const int wave = tid >> 6;
    const int lane = tid & 63;
    const int row = blockIdx.x * 4 + wave;      // 0..8191

    if (blockIdx.x == 0 && tid == 0) out[0] = 0.0f;

    const float4 a = ((const float4*)(z1 + (size_t)row * DIM))[lane];
    const float4 b = ((const float4*)(z2 + (size_t)row * DIM))[lane];

    auto wsum = [&](float v) -> float {
        #pragma unroll
        for (int m = 1; m < 64; m <<= 1) v += __shfl_xor(v, m, 64);
        return v;
    };

    const float na2 = wsum(a.x*a.x + a.y*a.y + a.z*a.z + a.w*a.w);
    const float nb2 = wsum(b.x*b.x + b.y*b.y + b.z*b.z + b.w*b.w);
    const float sa = 16.0f / sqrtf(na2);   // norms ~16; eps never binds
    const float sb = 16.0f / sqrtf(nb2);

    const float av[4] = {a.x*sa, a.y*sa, a.z*sa, a.w*sa};
    const float bv[4] = {b.x*sb, b.y*sb, b.z*sb, b.w*sb};
    unsigned char pa[4], pb[4];
    float qd = 0.0f;
    #pragma unroll
    for (int k = 0; k < 4; ++k) {
        __hip_fp8_e4m3 qa(av[k]);
        __hip_fp8_e4m3 qb(bv[k]);
        pa[k] = qa.__x; pb[k] = qb.__x;
        qd += float(qa) * float(qb);
    }
    const int g  = (lane >> 1) & 7;
    const int pp = ((g & 3) << 1) | (g >> 2);          // interleaved 8B slot
    const int off = (lane >> 4) * 64 + pp * 8 + (lane & 1) * 4;
    *(uchar4*)(Z8 + (size_t)row * DIM + off) = *(uchar4*)pa;
    *(uchar4*)(Z8 + (size_t)(N_ROWS + row) * DIM + off) = *(uchar4*)pb;

    qd = wsum(qd);
    if (lane == 0) pos[row] = qd * 0.00390625f;   // /256 -> quantized sim
}

// ---------------------------------------------------------------------------
// Kernel 2 (R14 = R10/R13 + VMEM-free loop): symmetric fp8 gram, 64x128
// tiles, strip-segmented SEGT=4, 2-slot __syncthreads prefetch ring, A in
// registers, raw v_exp_f32. R14 change: __syncthreads drains vmcnt(0),
// which includes the per-tile col-partial GLOBAL STORES (~400-600cy ack) —
// a store-drain serialized into every tile's barrier convoy. Fix: defer col
// partials to registers (colacc[4][4], +16 VGPR — free: R11 showed the VGPR
// quantum steps 64->128 and LDS already caps at 16 waves/CU, reachable at
// VGPR<=128). Tile loop fully unrolled with block-uniform (t < nt) guard so
// colacc stays register-allocated (rule #20). Steady-state loop now has
// ZERO VMEM except the 8 stage gload_lds per tile — each sync drains
// exactly what it must. All stores once at segment end.
// Spill tripwire (R8): FETCH must stay ~15.8MB.
// ---------------------------------------------------------------------------
template <bool TWO_STAGE>
__global__ __launch_bounds__(256, 4) void gram_kernel(
    const unsigned char* __restrict__ Z,
    float* __restrict__ part, float* __restrict__ S)
{
    // XCD band remap over segments (4224 = 8 * 528), then segment decode.
    const int sid = (blockIdx.x & 7) * (NSEG / 8) + (blockIdx.x >> 3);
    // group g: strips ri = 8g..8g+7 each have v = 32-g segments;
    // cum(g) = 260g - 4g^2 segments before group g.
    int g = (int)((260.0f - sqrtf(67600.0f - 16.0f * (float)sid)) * 0.125f);
    g = g < 0 ? 0 : (g > 31 ? 31 : g);
    while (260 * g - 4 * g * g > sid) --g;
    while (g < 31 && 260 * (g + 1) - 4 * (g + 1) * (g + 1) <= sid) ++g;
    const int local = sid - (260 * g - 4 * g * g);
    const int v  = 32 - g;                 // segments per strip in this group
    const int r8i = local / v;
    const int s4 = local - r8i * v;
    const int ri = 8 * g + r8i;            // row strip 0..255
    const int tj0 = (ri >> 1) + SEGT * s4; // first col tile
    const int nt = (NTILE - tj0 < SEGT) ? (NTILE - tj0) : SEGT;

    __shared__ unsigned char Ls[32768];   // B ring slots 0/1 (16KB each)

    const int tid  = threadIdx.x;
    const int wave = tid >> 6;
    const int lane = tid & 63;
    const int wr = wave >> 1, wc = wave & 1;   // wave grid 2x2 over 64x128
    const int lm = lane & 15, lq = lane >> 4;

    // ---- A fragments: global -> regs once per segment (R5/R7-proven layout)
    lx2 aR[2][2][2];                       // [kh][set][fr]
    {
        const unsigned char* pa =
            Z + (size_t)(ri * AT + wr * 32 + lm) * DIM + lq * 16;
        #pragma unroll
        for (int fr = 0; fr < 2; ++fr)
            #pragma unroll
            for (int kh = 0; kh < 2; ++kh)
                #pragma unroll
                for (int s = 0; s < 2; ++s)
                    aR[kh][s][fr] =
                        *(const lx2*)(pa + fr * 4096 + kh * 128 + s * 64);
    }

    // ---- staging lane geometry (width-16: 1KB instr = 8 rows x 8 granules)
    const int r8 = lane >> 3;                   // row within 8-row group
    const int pg = lane & 7;                    // LDS granule slot
    const int G0 = pg ^ (r8 >> 1);              // global granule, even instrs
    const int dlt = 64 - ((G0 & 4) << 5);       // odd instrs: granule G0^4
    const unsigned char* pB0 =
        Z + (size_t)(tj0 * BT + wave * 32 + r8) * DIM + (G0 << 4);

    auto stageB = [&](const unsigned char* pb, int kh, int sl) {
        #pragma unroll
        for (int c = 0; c < 4; ++c) {           // rows wave*32 + c*8 + r8
            const unsigned char* gb = ((c & 1) ? pb + dlt : pb) + c * 2048 + kh * 128;
            __builtin_amdgcn_global_load_lds(
                (const __attribute__((address_space(1))) void*)gb,
                (__attribute__((address_space(3))) void*)
                    (Ls + sl * 16384 + (wave * 4 + c) * 1024), 16, 0, 0);
        }
    };

    stageB(pB0, 0, 0);   // prologue: B(tile0, kh0) -> slot0

    // ---- B frag-read bases (invariant across the segment; R4 swizzle)
    const int s0 = (lq ^ (lm >> 1)) << 4;       // slot of granule lq
    const int s1 = s0 ^ 64;                     // slot of granule lq^4
    const unsigned char* LB = Ls + (wc * 64 + lm) * 128;   // + slot*16K

    const float SC = 2.8853900817779268f / 256.0f;   // exp(2*sim), dot=256*sim

    f32x4 rowacc[2] = {};        // per-lane row partial, over segment
    float colacc[SEGT][4] = {};  // per-lane col partials, static-indexed

    #pragma unroll
    for (int t = 0; t < SEGT; ++t) {
      if (t < nt) {              // block-uniform guard (nt from blockIdx)
        f32x4 acc[2][4] = {};
        #pragma unroll
        for (int kh = 0; kh < 2; ++kh) {
            __syncthreads();    // drains stage(h): only gload_lds in flight
            if (kh == 0)            stageB(pB0 + (size_t)t * 32768, 1, 1);
            else if (t + 1 < nt)    stageB(pB0 + (size_t)(t + 1) * 32768, 0, 0);

            const unsigned char* lb = LB + (kh << 14);   // slot == kh
            lx2 bP[4];
            __builtin_amdgcn_s_setprio(1);
            #pragma unroll
            for (int f = 0; f < 4; ++f) bP[f] = *(const lx2*)(lb + s0 + f * 2048);
            #pragma unroll
            for (int fr = 0; fr < 2; ++fr)
                #pragma unroll
                for (int fc = 0; fc < 4; ++fc) {
                    acc[fr][fc] = __builtin_amdgcn_mfma_f32_16x16x32_fp8_fp8(
                        aR[kh][0][fr].x, bP[fc].x, acc[fr][fc], 0, 0, 0);
                    acc[fr][fc] = __builtin_amdgcn_mfma_f32_16x16x32_fp8_fp8(
                        aR[kh][0][fr].y, bP[fc].y, acc[fr][fc], 0, 0, 0);
                }
            #pragma unroll
            for (int f = 0; f < 4; ++f) bP[f] = *(const lx2*)(lb + s1 + f * 2048);
            #pragma unroll
            for (int fr = 0; fr < 2; ++fr)
                #pragma unroll
                for (int fc = 0; fc < 4; ++fc) {
                    acc[fr][fc] = __builtin_amdgcn_mfma_f32_16x16x32_fp8_fp8(
                        aR[kh][1][fr].x, bP[fc].x, acc[fr][fc], 0, 0, 0);
                    acc[fr][fc] = __builtin_amdgcn_mfma_f32_16x16x32_fp8_fp8(
                        aR[kh][1][fr].y, bP[fc].y, acc[fr][fc], 0, 0, 0);
                }
            __builtin_amdgcn_s_setprio(0);
        }

        // ---- per-tile epilogue (register-only; no VMEM before next sync)
        #pragma unroll
        for (int fr = 0; fr < 2; ++fr)
            #pragma unroll
            for (int fc = 0; fc < 4; ++fc)
                #pragma unroll
                for (int r = 0; r < 4; ++r)
                    acc[fr][fc][r] = __builtin_amdgcn_exp2f(acc[fr][fc][r] * SC);

        if (t == 0 && s4 == 0) {   // only tile 0 of segment 0 crosses diagonal
            const int add = (ri & 1) << 6;    // odd strip: rows sit 64 below
            #pragma unroll
            for (int fr = 0; fr < 2; ++fr) {
                const int ciloc = wr * 32 + fr * 16 + lq * 4;
                #pragma unroll
                for (int fc = 0; fc < 4; ++fc) {
                    const int cj = wc * 64 + fc * 16 + lm;
                    #pragma unroll
                    for (int r = 0; r < 4; ++r)
                        if (cj <= ciloc + r + add) acc[fr][fc][r] = 0.0f;
                }
            }
        }

        // row partials: accumulate in registers across the segment
        #pragma unroll
        for (int fr = 0; fr < 2; ++fr)
            #pragma unroll
            for (int r = 0; r < 4; ++r)
                rowacc[fr][r] += acc[fr][0][r] + acc[fr][1][r]
                               + acc[fr][2][r] + acc[fr][3][r];

        // col partials: accumulate in registers (stores deferred to tail)
        #pragma unroll
        for (int fc = 0; fc < 4; ++fc) {
            float s_ = 0.0f;
            #pragma unroll
            for (int fr = 0; fr < 2; ++fr)
                #pragma unroll
                for (int r = 0; r < 4; ++r) s_ += acc[fr][fc][r];
            colacc[t][fc] = s_;
        }
      }
    }

    // ---- segment tail: all cross-lane reduces + stores (no barriers left)
    #pragma unroll
    for (int t = 0; t < SEGT; ++t)
        #pragma unroll
        for (int fc = 0; fc < 4; ++fc) {
            float s = colacc[t][fc];
            s += __shfl_xor(s, 16, 64);
            s += __shfl_xor(s, 32, 64);
            if (lq == 0) {      // 16 lanes x 4B consecutive = full 64B line
                const int cc = wc * 64 + fc * 16 + lm;
                if (TWO_STAGE)  // t>=nt slots write zeros; never read back
                    part[(size_t)sid * PSTRIDE + 128 + t * 256 + wr * 128 + cc] = s;
                else if (t < nt)
                    atomicAdd(&S[(tj0 + t) * BT + cc], s);
            }
        }

    float* dstr = TWO_STAGE ? (part + (size_t)sid * PSTRIDE) : nullptr;
    #pragma unroll
    for (int fr = 0; fr < 2; ++fr) {
        f32x4 rs;
        #pragma unroll
        for (int r = 0; r < 4; ++r) {
            float s = rowacc[fr][r];
            s += __shfl_xor(s, 1, 64);
            s += __shfl_xor(s, 2, 64);
            s += __shfl_xor(s, 4, 64);
            s += __shfl_xor(s, 8, 64);
            rs[r] = s;
        }
        if (lm == 0) {          // 4 lanes x 16B consecutive = full 64B line
            const int rr = wr * 32 + fr * 16 + lq * 4;
            if (TWO_STAGE) *(f32x4*)(dstr + wc * 64 + rr) = rs;
            else {
                #pragma unroll
                for (int r = 0; r < 4; ++r)
                    atomicAdd(&S[ri * AT + rr + r], rs[r]);
            }
        }
    }
}

// ---------------------------------------------------------------------------
// Kernel 3 (R13-proven): FUSED gather + loss, 1024 threads (16 waves/CU),
// 32-way m-stride -> worst block ~18 independent loads/lane, MLP-overlapped.
// Addressing verbatim from the R10-verified reduce_kernel. LDS fold padded
// stride-33 (conflict-free). out zeroed by normalize (stream-ordered).
// ---------------------------------------------------------------------------
__global__ __launch_bounds__(1024) void reduce_loss_kernel(
    const float* __restrict__ part, const float* __restrict__ pos,
    float* __restrict__ out)
{
    const int tid = threadIdx.x;
    const int j = tid & 31;              // row within block
    const int k = tid >> 5;              // stride lane 0..31
    const int i = blockIdx.x * 32 + j;   // row in [0, 8192)

    __shared__ float red1[32 * 33], red2[32 * 33];

    float den[2];
    #pragma unroll
    for (int h = 0; h < 2; ++h) {
        const int r = i + h * N_ROWS;    // Z row
        const int ri = r >> 6, rr = r & 63;
        const int gg = ri >> 3;
        const int nseg = 32 - gg;
        const int sid0 = 260 * gg - 4 * gg * gg + (ri & 7) * nseg;
        const int tj = r >> 7, cc = r & 127;
        const int nr = 2 * tj + 2;       // strips covering col tile tj
        const int T = 2 * nseg + 2 * nr;

        float s = 0.0f;
        for (int m = k; m < T; m += 32) {
            size_t addr;
            if (m < 2 * nseg) {
                addr = (size_t)(sid0 + (m >> 1)) * PSTRIDE + (m & 1) * 64 + rr;
            } else {
                const int m2 = m - 2 * nseg;
                const int rip = m2 >> 1;            // source strip
                const int dtj = tj - (rip >> 1);
                const int gp = rip >> 3;
                const int sidc = 260 * gp - 4 * gp * gp + (rip & 7) * (32 - gp)
                               + (dtj >> 2);
                addr = (size_t)sidc * PSTRIDE + 128 + (dtj & 3) * 256
                     + (m2 & 1) * 128 + cc;
            }
            s += part[addr];
        }
        den[h] = s;
    }
    red1[j * 33 + k] = den[0];
    red2[j * 33 + k] = den[1];
    __syncthreads();

    if (tid < 32) {
        float d1 = 0.0f, d2 = 0.0f;
        #pragma unroll
        for (int kk = 0; kk < 32; ++kk) {
            d1 += red1[tid * 33 + kk];
            d2 += red2[tid * 33 + kk];
        }
        float vv = 0.5f * (logf(d1) + logf(d2))
                 - TAU_INV * pos[blockIdx.x * 32 + tid];
        vv += __shfl_xor(vv, 1, 64);
        vv += __shfl_xor(vv, 2, 64);
        vv += __shfl_xor(vv, 4, 64);
        vv += __shfl_xor(vv, 8, 64);
        vv += __shfl_xor(vv, 16, 64);
        if (tid == 0) atomicAdd(out, vv * (1.0f / N_ROWS));
    }
}

// Fallback loss (atomic path, only if ws too small — never expected).
__global__ __launch_bounds__(256) void loss_kernel(
    const float* __restrict__ S, const float* __restrict__ pos,
    float* __restrict__ out)
{
    const int i = blockIdx.x * 256 + threadIdx.x;
    float v = 0.5f * (logf(S[i]) + logf(S[N_ROWS + i])) - TAU_INV * pos[i];

    __shared__ float red[4];
    #pragma unroll
    for (int m = 1; m < 64; m <<= 1) v += __shfl_xor(v, m, 64);
    if ((threadIdx.x & 63) == 0) red[threadIdx.x >> 6] = v;
    __syncthreads();
    if (threadIdx.x == 0)
        atomicAdd(out, (red[0] + red[1] + red[2] + red[3]) * (1.0f / N_ROWS));
}

// ---------------------------------------------------------------------------
extern "C" void kernel_launch(void* const* d_in, const int* in_sizes, int n_in,
                              void* d_out, int out_size, void* d_ws, size_t ws_size,
                              hipStream_t stream)
{
    const float* z1 = (const float*)d_in[0];
    const float* z2 = (const float*)d_in[1];
    float* out = (float*)d_out;

    char* ws = (char*)d_ws;
    unsigned char* Z8 = (unsigned char*)ws;              // 16384*256 = 4 MB
    float* pos  = (float*)(ws + 4194304);                // 32 KB
    float* S    = (float*)(ws + 4227072);                // NZ floats (fallback)
    float* part = (float*)(ws + 5275648);                // 4224*1152*4 = 19.5 MB
    const size_t need = 5275648 + (size_t)NSEG * PSTRIDE * 4;

    normalize_kernel<<<N_ROWS / 4, 256, 0, stream>>>(z1, z2, Z8, pos, out);

    if (ws_size >= need) {
        gram_kernel<true><<<NSEG, 256, 0, stream>>>(Z8, part, nullptr);
        reduce_loss_kernel<<<N_ROWS / 32, 1024, 0, stream>>>(part, pos, out);
    } else {
        hipMemsetAsync(S, 0, NZ * sizeof(float), stream);
        hipMemsetAsync(out, 0, sizeof(float), stream);
        gram_kernel<false><<<NSEG, 256, 0, stream>>>(Z8, nullptr, S);
        loss_kernel<<<N_ROWS / 256, 256, 0, stream>>>(S, pos, out);
    }
}